// Round 13
// baseline (563.101 us; speedup 1.0000x reference)
//
#include <hip/hip_runtime.h>

typedef __bf16 bf16x8 __attribute__((ext_vector_type(8)));
typedef __bf16 bf16x4 __attribute__((ext_vector_type(4)));
typedef float  f32x4  __attribute__((ext_vector_type(4)));

#define T_TOT 4096
#define SEQ   1024
#define BATCH 4
#define HEADS 16
#define DIM   128
#define HIDN  2048
#define QKVW  6144

__device__ __forceinline__ void gld_lds16(const void* g, void* l) {
  __builtin_amdgcn_global_load_lds(
      (const __attribute__((address_space(1))) unsigned int*)g,
      (__attribute__((address_space(3))) unsigned int*)l, 16, 0, 0);
}

// ---------------- merged f32 -> bf16 conversions (one launch) ----------------
__global__ void f2b_all(const float* __restrict__ h,  __bf16* __restrict__ oh,
                        const float* __restrict__ wa, __bf16* __restrict__ owa,
                        const float* __restrict__ wp, __bf16* __restrict__ owp)
{
  const int bid = blockIdx.x;
  const float* in;
  __bf16* out;
  int base;
  if (bid < 8192)       { in = h;  out = oh;  base = bid; }
  else if (bid < 20480) { in = wa; out = owa; base = bid - 8192; }
  else                  { in = wp; out = owp; base = bid - 20480; }
  const int i = (base * 256 + threadIdx.x) * 4;
  const float4 v = *(const float4*)(in + i);
  bf16x4 o;
  o[0] = (__bf16)v.x; o[1] = (__bf16)v.y; o[2] = (__bf16)v.z; o[3] = (__bf16)v.w;
  *(bf16x4*)(out + i) = o;
}

// ======== gemm1: BM=256 BN=128 BK=32, 4 waves, wave-tile 128x64 ========
// 48KB double-buffer -> 3 blocks/CU (12 waves/CU TLP, zero grid tail at
// 768 blocks). Lead-1 gld_lds staging, per-tile vmcnt(0) drain (covered by
// TLP), ONE barrier/tile, frag prefetch after barrier (race-free).
template<int BIAS, typename OUT_T>
__global__ __launch_bounds__(256, 3) void gemm1(
    const __bf16* __restrict__ A, int lda,
    const __bf16* __restrict__ B, int ldb,
    const float* __restrict__ bias,
    OUT_T* __restrict__ C, int ldc, int K, int nby)
{
  __shared__ __bf16 sA[2 * 256 * 32];   // 32 KB
  __shared__ __bf16 sB[2 * 128 * 32];   // 16 KB
  const int tid = threadIdx.x;
  const int w = tid >> 6, lane = tid & 63;
  const int lq = lane & 15, lg = lane >> 4;
  const int wm = w >> 1, wn = w & 1;

  // bijective XCD swizzle (gridDim.x % 8 == 0); M-major chunks per XCD
  const int nwg = gridDim.x, cpx = nwg >> 3, bid = blockIdx.x;
  const int wgid = (bid & 7) * cpx + (bid >> 3);
  const int by = wgid % nby, bx = wgid / nby;
  const int bm = by * 256, bn = bx * 128;

  // staging: one issue = 256 thr x 16B = 64 rows x 64B
  const int srow = tid >> 2;                             // 0..63
  const int scol = ((tid & 3) ^ ((srow >> 1) & 3)) * 8;  // pre-swizzled col
  const __bf16* gA = A + (size_t)(bm + srow) * lda + scol;
  const __bf16* gB = B + (size_t)(bn + srow) * ldb + scol;
  const int w16 = w * 16;
  const int NT = K >> 5;

#define STAGE(t, bf) {                                                    \
    const __bf16* sa_ = gA + (size_t)(t) * 32;                            \
    gld_lds16(sa_,                     &sA[(bf) * 8192 + (w16) * 32]);    \
    gld_lds16(sa_ + (size_t) 64 * lda, &sA[(bf) * 8192 + (64 + w16) * 32]); \
    gld_lds16(sa_ + (size_t)128 * lda, &sA[(bf) * 8192 + (128 + w16) * 32]); \
    gld_lds16(sa_ + (size_t)192 * lda, &sA[(bf) * 8192 + (192 + w16) * 32]); \
    const __bf16* sb_ = gB + (size_t)(t) * 32;                            \
    gld_lds16(sb_,                     &sB[(bf) * 4096 + (w16) * 32]);    \
    gld_lds16(sb_ + (size_t) 64 * ldb, &sB[(bf) * 4096 + (64 + w16) * 32]); }

  f32x4 acc[8][4] = {};

  // ds_read: stored granule = lg ^ ((row>>1)&3); row = base16 + lq
  const int colo = (lg ^ ((lq >> 1) & 3)) * 8;
  const int offA = (wm * 128 + lq) * 32 + colo;
  const int offB = (wn * 64 + lq) * 32 + colo;

  STAGE(0, 0);
  asm volatile("s_waitcnt vmcnt(0)" ::: "memory");
  __builtin_amdgcn_s_barrier();
  asm volatile("" ::: "memory");

  bf16x8 a[8], b[4];
  {
    const __bf16* pA = &sA[offA];
    const __bf16* pB = &sB[offB];
#pragma unroll
    for (int m = 0; m < 8; ++m) a[m] = *(const bf16x8*)(pA + m * 512);
#pragma unroll
    for (int n = 0; n < 4; ++n) b[n] = *(const bf16x8*)(pB + n * 512);
  }

  for (int t = 0; t < NT; ++t) {
    if (t + 1 < NT) STAGE(t + 1, (t + 1) & 1);

    asm volatile("s_waitcnt lgkmcnt(0)" ::: "memory");
    __builtin_amdgcn_sched_barrier(0);
    __builtin_amdgcn_s_setprio(1);
#pragma unroll
    for (int m = 0; m < 8; ++m)
#pragma unroll
      for (int n = 0; n < 4; ++n)
        acc[m][n] = __builtin_amdgcn_mfma_f32_16x16x32_bf16(a[m], b[n], acc[m][n], 0, 0, 0);
    __builtin_amdgcn_s_setprio(0);

    if (t + 1 < NT) {
      asm volatile("s_waitcnt vmcnt(0)" ::: "memory");   // my stage(t+1) landed
      __builtin_amdgcn_s_barrier();                      // everyone's landed
      asm volatile("" ::: "memory");
      const int bnext = (t + 1) & 1;
      const __bf16* pA = &sA[bnext * 8192 + offA];
      const __bf16* pB = &sB[bnext * 4096 + offB];
#pragma unroll
      for (int m = 0; m < 8; ++m) a[m] = *(const bf16x8*)(pA + m * 512);
#pragma unroll
      for (int n = 0; n < 4; ++n) b[n] = *(const bf16x8*)(pB + n * 512);
    }
  }
#undef STAGE

  // epilogue (wave-tile 128x64)
#pragma unroll
  for (int n = 0; n < 4; ++n) {
    const int col = bn + wn * 64 + n * 16 + lq;
    const float bv = BIAS ? bias[col] : 0.0f;
#pragma unroll
    for (int m = 0; m < 8; ++m)
#pragma unroll
      for (int r = 0; r < 4; ++r) {
        const int row = bm + wm * 128 + m * 16 + lg * 4 + r;
        C[(size_t)row * ldc + col] = (OUT_T)(acc[m][n][r] + bv);
      }
  }
}

// ======== gemm_sq: BM=BN=128 BK=32, 4 waves, wave-tile 64x64 ========
// 48KB triple-buffer, lead-2 counted vmcnt(4); grid 512 = full machine,
// single round. Same swizzle pair and race-free prefetch ordering.
template<int BIAS, typename OUT_T>
__global__ __launch_bounds__(256, 3) void gemm_sq(
    const __bf16* __restrict__ A, int lda,
    const __bf16* __restrict__ B, int ldb,
    const float* __restrict__ bias,
    OUT_T* __restrict__ C, int ldc, int K, int nby)
{
  __shared__ __bf16 sA[3 * 128 * 32];   // 24 KB
  __shared__ __bf16 sB[3 * 128 * 32];   // 24 KB
  const int tid = threadIdx.x;
  const int w = tid >> 6, lane = tid & 63;
  const int lq = lane & 15, lg = lane >> 4;
  const int wm = w >> 1, wn = w & 1;

  const int nwg = gridDim.x, cpx = nwg >> 3, bid = blockIdx.x;
  const int wgid = (bid & 7) * cpx + (bid >> 3);
  const int by = wgid % nby, bx = wgid / nby;
  const int bm = by * 128, bn = bx * 128;

  const int srow = tid >> 2;
  const int scol = ((tid & 3) ^ ((srow >> 1) & 3)) * 8;
  const __bf16* gA = A + (size_t)(bm + srow) * lda + scol;
  const __bf16* gB = B + (size_t)(bn + srow) * ldb + scol;
  const int w16 = w * 16;
  const int NT = K >> 5;

#define STAGE(t, bf) {                                                    \
    const __bf16* sa_ = gA + (size_t)(t) * 32;                            \
    gld_lds16(sa_,                     &sA[(bf) * 4096 + (w16) * 32]);    \
    gld_lds16(sa_ + (size_t)64 * lda,  &sA[(bf) * 4096 + (64 + w16) * 32]); \
    const __bf16* sb_ = gB + (size_t)(t) * 32;                            \
    gld_lds16(sb_,                     &sB[(bf) * 4096 + (w16) * 32]);    \
    gld_lds16(sb_ + (size_t)64 * ldb,  &sB[(bf) * 4096 + (64 + w16) * 32]); }

  f32x4 acc[4][4] = {};

  const int colo = (lg ^ ((lq >> 1) & 3)) * 8;
  const int offA = (wm * 64 + lq) * 32 + colo;
  const int offB = (wn * 64 + lq) * 32 + colo;

  STAGE(0, 0); STAGE(1, 1);
  asm volatile("s_waitcnt vmcnt(4)" ::: "memory");   // tile0's 4 loads landed
  __builtin_amdgcn_s_barrier();
  asm volatile("" ::: "memory");

  bf16x8 a[4], b[4];
  {
    const __bf16* pA = &sA[offA];
    const __bf16* pB = &sB[offB];
#pragma unroll
    for (int m = 0; m < 4; ++m) a[m] = *(const bf16x8*)(pA + m * 512);
#pragma unroll
    for (int n = 0; n < 4; ++n) b[n] = *(const bf16x8*)(pB + n * 512);
  }

  int bcur = 0;
  for (int t = 0; t < NT; ++t) {
    int bstg = bcur + 2; if (bstg >= 3) bstg -= 3;
    const bool st = (t + 2) < NT;
    if (st) STAGE(t + 2, bstg);

    asm volatile("s_waitcnt lgkmcnt(0)" ::: "memory");
    __builtin_amdgcn_sched_barrier(0);
    __builtin_amdgcn_s_setprio(1);
#pragma unroll
    for (int m = 0; m < 4; ++m)
#pragma unroll
      for (int n = 0; n < 4; ++n)
        acc[m][n] = __builtin_amdgcn_mfma_f32_16x16x32_bf16(a[m], b[n], acc[m][n], 0, 0, 0);
    __builtin_amdgcn_s_setprio(0);

    if (t + 1 < NT) {
      if (st) { asm volatile("s_waitcnt vmcnt(4)" ::: "memory"); }
      else    { asm volatile("s_waitcnt vmcnt(0)" ::: "memory"); }
      __builtin_amdgcn_s_barrier();
      asm volatile("" ::: "memory");
      const int bnext = (bcur + 1 == 3) ? 0 : bcur + 1;
      const __bf16* pA = &sA[bnext * 4096 + offA];
      const __bf16* pB = &sB[bnext * 4096 + offB];
#pragma unroll
      for (int m = 0; m < 4; ++m) a[m] = *(const bf16x8*)(pA + m * 512);
#pragma unroll
      for (int n = 0; n < 4; ++n) b[n] = *(const bf16x8*)(pB + n * 512);
    }
    bcur = (bcur + 1 == 3) ? 0 : bcur + 1;
  }
#undef STAGE

#pragma unroll
  for (int n = 0; n < 4; ++n) {
    const int col = bn + wn * 64 + n * 16 + lq;
    const float bv = BIAS ? bias[col] : 0.0f;
#pragma unroll
    for (int m = 0; m < 4; ++m)
#pragma unroll
      for (int r = 0; r < 4; ++r) {
        const int row = bm + wm * 64 + m * 16 + lg * 4 + r;
        C[(size_t)row * ldc + col] = (OUT_T)(acc[m][n][r] + bv);
      }
  }
}

// ---------------- pack: RoPE(Q,K) -> Qp/Kp [bh][s][d]; V -> Vt [bh][d][s] ----------------
__global__ __launch_bounds__(256) void pack_kernel(const __bf16* __restrict__ qkv,
                                                   const float* __restrict__ cosb,
                                                   const float* __restrict__ sinb,
                                                   __bf16* __restrict__ Qp,
                                                   __bf16* __restrict__ Kp,
                                                   __bf16* __restrict__ Vt)
{
  __shared__ __bf16 tile[64][136];
  const int bh = blockIdx.y, b = bh >> 4, h = bh & 15;
  const int s0 = blockIdx.x * 64;
  const int tid = threadIdx.x;
  const int j0 = (tid & 7) * 8;
  const float qsc = 0.08838834764831845f;  // 1/sqrt(128)

#pragma unroll
  for (int it = 0; it < 2; ++it) {
    const int r = (tid >> 3) + it * 32;
    const int s = s0 + r;
    const size_t t = (size_t)b * SEQ + s;
    float cc[8], ss[8];
    *(float4*)&cc[0] = *(const float4*)&cosb[t * 64 + j0];
    *(float4*)&cc[4] = *(const float4*)&cosb[t * 64 + j0 + 4];
    *(float4*)&ss[0] = *(const float4*)&sinb[t * 64 + j0];
    *(float4*)&ss[4] = *(const float4*)&sinb[t * 64 + j0 + 4];
    const __bf16* src = qkv + t * QKVW + h * DIM;
    const bf16x8 q1 = *(const bf16x8*)(src + j0);
    const bf16x8 q2 = *(const bf16x8*)(src + 64 + j0);
    const bf16x8 k1 = *(const bf16x8*)(src + HIDN + j0);
    const bf16x8 k2 = *(const bf16x8*)(src + HIDN + 64 + j0);
    bf16x8 oq1, oq2, ok1, ok2;
#pragma unroll
    for (int jj = 0; jj < 8; ++jj) {
      const float c = cc[jj], sn = ss[jj];
      const float a1 = (float)q1[jj], a2 = (float)q2[jj];
      const float b1 = (float)k1[jj], b2 = (float)k2[jj];
      oq1[jj] = (__bf16)((a1 * c - a2 * sn) * qsc);
      oq2[jj] = (__bf16)((a2 * c + a1 * sn) * qsc);
      ok1[jj] = (__bf16)(b1 * c - b2 * sn);
      ok2[jj] = (__bf16)(b2 * c + b1 * sn);
    }
    __bf16* dq = Qp + ((size_t)bh * SEQ + s) * DIM + j0;
    __bf16* dk = Kp + ((size_t)bh * SEQ + s) * DIM + j0;
    *(bf16x8*)dq = oq1; *(bf16x8*)(dq + 64) = oq2;
    *(bf16x8*)dk = ok1; *(bf16x8*)(dk + 64) = ok2;
  }

#pragma unroll
  for (int i = 0; i < 4; ++i) {
    const int r = (tid >> 4) + i * 16;
    const int c = (tid & 15) * 8;
    *(bf16x8*)&tile[r][c] =
        *(const bf16x8*)&qkv[((size_t)b * SEQ + s0 + r) * QKVW + 2 * HIDN + h * DIM + c];
  }
  __syncthreads();
#pragma unroll
  for (int i = 0; i < 4; ++i) {
    const int d = (tid >> 3) + i * 32;
    const int scc = (tid & 7) * 8;
    bf16x8 v;
#pragma unroll
    for (int jj = 0; jj < 8; ++jj) v[jj] = tile[scc + jj][d];
    *(bf16x8*)&Vt[((size_t)bh * DIM + d) * SEQ + s0 + scc] = v;
  }
}

// ---------------- causal flash attention v3 (unchanged) ----------------
__global__ __launch_bounds__(256, 2) void attn_kernel(const __bf16* __restrict__ Qp,
                                                      const __bf16* __restrict__ Kp,
                                                      const __bf16* __restrict__ Vt,
                                                      __bf16* __restrict__ O)
{
  __shared__ __bf16 sK[2][64 * 128];   // 32 KB
  __shared__ __bf16 sV[2][128 * 64];   // 32 KB
  __shared__ __bf16 sP[4][32 * 64];    // 16 KB (XOR-swizzled)
  const int w = threadIdx.x >> 6, lane = threadIdx.x & 63;
  const int lq = lane & 15, lg = lane >> 4;
  const int bh = blockIdx.y, b = bh >> 4, h = bh & 15;
  const int qb = ((int)blockIdx.x + bh) & 7;
  const int q0 = qb * 128 + w * 32;
  const int NTb = 2 * qb + 2;
  const int kend = q0 + 32;

  const __bf16* Qh = Qp + (size_t)bh * SEQ * DIM;
  const __bf16* Kh = Kp + (size_t)bh * SEQ * DIM;
  const __bf16* Vh = Vt + (size_t)bh * DIM * SEQ;

  const int krow = lane >> 4;
  const int kgr  = lane & 15;
  const int vrow = lane >> 3;
  const int vgr  = lane & 7;
  const __bf16* Vsrc = Vh + (size_t)(w * 32 + vrow) * SEQ + (vgr ^ vrow) * 8;

  auto ASTAGE = [&](int ktn, int p) {
#pragma unroll
    for (int i = 0; i < 4; ++i) {
      const int rb = w * 16 + i * 4;
      gld_lds16(Kh + (size_t)(ktn + rb + krow) * DIM + (kgr ^ (i * 4 + krow)) * 8,
                &sK[p][rb * DIM]);
    }
#pragma unroll
    for (int i = 0; i < 4; ++i) {
      gld_lds16(Vsrc + (size_t)i * 8 * SEQ + ktn, &sV[p][(w * 32 + i * 8) * 64]);
    }
  };

  bf16x8 aq[2][4];
#pragma unroll
  for (int m = 0; m < 2; ++m)
#pragma unroll
    for (int kk = 0; kk < 4; ++kk)
      aq[m][kk] = *(const bf16x8*)(Qh + (size_t)(q0 + m * 16 + lq) * DIM + kk * 32 + lg * 8);

  f32x4 accO[2][8] = {};
  float mrow[2][4], lrow[2][4];
#pragma unroll
  for (int m = 0; m < 2; ++m)
#pragma unroll
    for (int r = 0; r < 4; ++r) { mrow[m][r] = -1e30f; lrow[m][r] = 0.0f; }

  ASTAGE(0, 0);
  asm volatile("s_waitcnt vmcnt(0)" ::: "memory");
  __builtin_amdgcn_s_barrier();

  int p = 0;
  for (int t = 0; t < NTb; ++t) {
    const int kt = t * 64;
    if (t + 1 < NTb) ASTAGE(kt + 64, p ^ 1);

    if (kt < kend) {
      f32x4 s[2][4] = {};
#pragma unroll
      for (int n = 0; n < 4; ++n) {
        const int rowb = (n * 16 + lq) * DIM;
#pragma unroll
        for (int kk = 0; kk < 4; ++kk) {
          const bf16x8 bk = *(const bf16x8*)&sK[p][rowb + ((4 * kk + lg) ^ lq) * 8];
#pragma unroll
          for (int m = 0; m < 2; ++m)
            s[m][n] = __builtin_amdgcn_mfma_f32_16x16x32_bf16(aq[m][kk], bk, s[m][n], 0, 0, 0);
        }
      }
      if (kt + 63 > q0) {
#pragma unroll
        for (int n = 0; n < 4; ++n) {
          const int kpos = kt + n * 16 + lq;
#pragma unroll
          for (int m = 0; m < 2; ++m)
#pragma unroll
            for (int r = 0; r < 4; ++r)
              if (kpos > q0 + m * 16 + lg * 4 + r) s[m][n][r] = -1e30f;
        }
      }
#pragma unroll
      for (int m = 0; m < 2; ++m) {
#pragma unroll
        for (int r = 0; r < 4; ++r) {
          float mx = fmaxf(fmaxf(s[m][0][r], s[m][1][r]), fmaxf(s[m][2][r], s[m][3][r]));
          mx = fmaxf(mx, __shfl_xor(mx, 1));
          mx = fmaxf(mx, __shfl_xor(mx, 2));
          mx = fmaxf(mx, __shfl_xor(mx, 4));
          mx = fmaxf(mx, __shfl_xor(mx, 8));
          const float mnew = fmaxf(mrow[m][r], mx);
          const float alpha = __expf(mrow[m][r] - mnew);
          mrow[m][r] = mnew;
          float rs = 0.0f;
#pragma unroll
          for (int n = 0; n < 4; ++n) {
            const float pv = __expf(s[m][n][r] - mnew);
            s[m][n][r] = pv;
            rs += pv;
          }
          rs += __shfl_xor(rs, 1); rs += __shfl_xor(rs, 2);
          rs += __shfl_xor(rs, 4); rs += __shfl_xor(rs, 8);
          lrow[m][r] = lrow[m][r] * alpha + rs;
#pragma unroll
          for (int f = 0; f < 8; ++f) accO[m][f][r] *= alpha;
        }
      }
#pragma unroll
      for (int m = 0; m < 2; ++m)
#pragma unroll
        for (int n = 0; n < 4; ++n)
#pragma unroll
          for (int r = 0; r < 4; ++r) {
            const int prow = m * 16 + lg * 4 + r;
            const int cb = (n * 16 + lq) * 2;
            const int addr = prow * 128 + (((cb >> 4) ^ (prow & 7)) << 4) + (cb & 15);
            *(__bf16*)((char*)&sP[w][0] + addr) = (__bf16)s[m][n][r];
          }
      asm volatile("s_waitcnt lgkmcnt(0)" ::: "memory");
#pragma unroll
      for (int kk2 = 0; kk2 < 2; ++kk2) {
        bf16x8 ap[2];
#pragma unroll
        for (int m = 0; m < 2; ++m) {
          const int prow = m * 16 + lq;
          ap[m] = *(const bf16x8*)((char*)&sP[w][0] +
                   prow * 128 + (((4 * kk2 + lg) ^ (lq & 7)) << 4));
        }
#pragma unroll
        for (int f = 0; f < 8; ++f) {
          const bf16x8 bv = *(const bf16x8*)&sV[p][(f * 16 + lq) * 64 +
                                                   ((4 * kk2 + lg) ^ (lq & 7)) * 8];
#pragma unroll
          for (int m = 0; m < 2; ++m)
            accO[m][f] = __builtin_amdgcn_mfma_f32_16x16x32_bf16(ap[m], bv, accO[m][f], 0, 0, 0);
        }
      }
    }
    asm volatile("s_waitcnt vmcnt(0)" ::: "memory");
    __builtin_amdgcn_s_barrier();
    p ^= 1;
  }

#pragma unroll
  for (int m = 0; m < 2; ++m)
#pragma unroll
    for (int f = 0; f < 8; ++f)
#pragma unroll
      for (int r = 0; r < 4; ++r) {
        const float v = accO[m][f][r] / lrow[m][r];
        O[((size_t)b * SEQ + q0 + m * 16 + lg * 4 + r) * HIDN + h * DIM + f * 16 + lq] = (__bf16)v;
      }
}

// ---------------- launch ----------------
extern "C" void kernel_launch(void* const* d_in, const int* in_sizes, int n_in,
                              void* d_out, int out_size, void* d_ws, size_t ws_size,
                              hipStream_t stream)
{
  const float* hidden = (const float*)d_in[0];
  const float* cosb   = (const float*)d_in[1];
  const float* sinb   = (const float*)d_in[2];
  const float* w_attn = (const float*)d_in[3];
  const float* b_attn = (const float*)d_in[4];
  const float* w_proj = (const float*)d_in[5];

  char* ws = (char*)d_ws;
  __bf16* hid_bf   = (__bf16*)(ws);                 // [0, 16M)
  __bf16* wattn_bf = (__bf16*)(ws + 16777216);      // [16M, 40M)
  __bf16* wproj_bf = (__bf16*)(ws + 41943040);      // [40M, 48M)
  __bf16* qkv      = (__bf16*)(ws + 50331648);      // [48M, 96M)
  __bf16* Qp       = (__bf16*)(ws);                 // [0, 16M)  (reuse, post-GEMM1)
  __bf16* Kp       = (__bf16*)(ws + 16777216);      // [16M, 32M)
  __bf16* Vt       = (__bf16*)(ws + 100663296);     // [96M, 112M)
  __bf16* Obuf     = (__bf16*)(ws + 117440512);     // [112M, 128M)
  float* out = (float*)d_out;

  f2b_all<<<24576, 256, 0, stream>>>(hidden, hid_bf, w_attn, wattn_bf, w_proj, wproj_bf);

  // qkv = hidden @ w_attn^T + b   (M=4096, N=6144, K=2048): 16x48 = 768 blocks
  gemm1<1, __bf16><<<768, 256, 0, stream>>>(
      hid_bf, HIDN, wattn_bf, HIDN, b_attn, qkv, QKVW, HIDN, 16);

  pack_kernel<<<dim3(16, 64), 256, 0, stream>>>(qkv, cosb, sinb, Qp, Kp, Vt);
  attn_kernel<<<dim3(8, 64), 256, 0, stream>>>(Qp, Kp, Vt, Obuf);

  // out = O @ w_proj^T   (M=4096, N=2048, K=2048): 32x16 = 512 blocks, f32 out
  gemm_sq<0, float><<<512, 256, 0, stream>>>(
      Obuf, HIDN, wproj_bf, HIDN, nullptr, out, HIDN, HIDN, 32);
}

// Round 14
// 270.009 us; speedup vs baseline: 2.0855x; 2.0855x over previous
//
#include <hip/hip_runtime.h>

typedef __bf16 bf16x8 __attribute__((ext_vector_type(8)));
typedef __bf16 bf16x4 __attribute__((ext_vector_type(4)));
typedef float  f32x4  __attribute__((ext_vector_type(4)));

#define T_TOT 4096
#define SEQ   1024
#define BATCH 4
#define HEADS 16
#define DIM   128
#define HIDN  2048
#define QKVW  6144

__device__ __forceinline__ void gld_lds16(const void* g, void* l) {
  __builtin_amdgcn_global_load_lds(
      (const __attribute__((address_space(1))) unsigned int*)g,
      (__attribute__((address_space(3))) unsigned int*)l, 16, 0, 0);
}

// ---------------- merged f32 -> bf16 conversions (one launch) ----------------
__global__ void f2b_all(const float* __restrict__ h,  __bf16* __restrict__ oh,
                        const float* __restrict__ wa, __bf16* __restrict__ owa,
                        const float* __restrict__ wp, __bf16* __restrict__ owp)
{
  const int bid = blockIdx.x;
  const float* in;
  __bf16* out;
  int base;
  if (bid < 8192)       { in = h;  out = oh;  base = bid; }
  else if (bid < 20480) { in = wa; out = owa; base = bid - 8192; }
  else                  { in = wp; out = owp; base = bid - 20480; }
  const int i = (base * 256 + threadIdx.x) * 4;
  const float4 v = *(const float4*)(in + i);
  bf16x4 o;
  o[0] = (__bf16)v.x; o[1] = (__bf16)v.y; o[2] = (__bf16)v.z; o[3] = (__bf16)v.w;
  *(bf16x4*)(out + i) = o;
}

// ======== gemm_wide (PROVEN round-11, 127us): BM=256 BN=128 BK=32 ========
// 4 waves, wave-tile 128x64 (needs ~200 unified regs -> MAX 2 blocks/CU;
// (256,3) spills acc to scratch, round-13 lesson). 72KB triple-buffer,
// lead-2 counted vmcnt(6), ONE barrier/tile, frag prefetch after barrier.
template<int BIAS, typename OUT_T>
__global__ __launch_bounds__(256, 2) void gemm_wide(
    const __bf16* __restrict__ A, int lda,
    const __bf16* __restrict__ B, int ldb,
    const float* __restrict__ bias,
    OUT_T* __restrict__ C, int ldc, int K, int nby)
{
  __shared__ __bf16 sA[3 * 256 * 32];   // 48 KB
  __shared__ __bf16 sB[3 * 128 * 32];   // 24 KB
  const int tid = threadIdx.x;
  const int w = tid >> 6, lane = tid & 63;
  const int lq = lane & 15, lg = lane >> 4;
  const int wm = w >> 1, wn = w & 1;

  // bijective XCD swizzle (gridDim.x % 8 == 0); M-major chunks per XCD
  const int nwg = gridDim.x, cpx = nwg >> 3, bid = blockIdx.x;
  const int wgid = (bid & 7) * cpx + (bid >> 3);
  const int by = wgid % nby, bx = wgid / nby;
  const int bm = by * 256, bn = bx * 128;

  // staging: one issue = 256 thr x 16B = 64 rows x 64B
  const int srow = tid >> 2;                             // 0..63
  const int scol = ((tid & 3) ^ ((srow >> 1) & 3)) * 8;  // pre-swizzled col
  const __bf16* gA = A + (size_t)(bm + srow) * lda + scol;
  const __bf16* gB = B + (size_t)(bn + srow) * ldb + scol;
  __bf16* dA = &sA[w * 512];
  __bf16* dB = &sB[w * 512];

  const int NT = K >> 5;

#define STAGE(t, bf) {                                               \
    const __bf16* sa_ = gA + (size_t)(t) * 32;                       \
    gld_lds16(sa_,                      dA + (bf) * 8192);           \
    gld_lds16(sa_ + (size_t) 64 * lda,  dA + (bf) * 8192 + 2048);    \
    gld_lds16(sa_ + (size_t)128 * lda,  dA + (bf) * 8192 + 4096);    \
    gld_lds16(sa_ + (size_t)192 * lda,  dA + (bf) * 8192 + 6144);    \
    const __bf16* sb_ = gB + (size_t)(t) * 32;                       \
    gld_lds16(sb_,                      dB + (bf) * 4096);           \
    gld_lds16(sb_ + (size_t) 64 * ldb,  dB + (bf) * 4096 + 2048); }

  f32x4 acc[8][4] = {};

  // ds_read: stored granule = lg ^ ((row>>1)&3); row = base16 + lq
  const int colo = (lg ^ ((lq >> 1) & 3)) * 8;
  const int offA = (wm * 128 + lq) * 32 + colo;
  const int offB = (wn * 64 + lq) * 32 + colo;

  STAGE(0, 0); STAGE(1, 1);
  asm volatile("s_waitcnt vmcnt(6)" ::: "memory");   // tile0 landed
  __builtin_amdgcn_s_barrier();
  asm volatile("" ::: "memory");

  bf16x8 a[8], b[4];
  {
    const __bf16* pA = &sA[offA];
    const __bf16* pB = &sB[offB];
#pragma unroll
    for (int m = 0; m < 8; ++m) a[m] = *(const bf16x8*)(pA + m * 512);
#pragma unroll
    for (int n = 0; n < 4; ++n) b[n] = *(const bf16x8*)(pB + n * 512);
  }

  int bcur = 0;
  for (int t = 0; t < NT; ++t) {
    int bstg = bcur + 2; if (bstg >= 3) bstg -= 3;
    const bool st = (t + 2) < NT;
    if (st) STAGE(t + 2, bstg);   // buf(t-1): readers drained at end-of-(t-1) barrier

    asm volatile("s_waitcnt lgkmcnt(0)" ::: "memory");
    __builtin_amdgcn_sched_barrier(0);
    __builtin_amdgcn_s_setprio(1);
#pragma unroll
    for (int m = 0; m < 8; ++m)
#pragma unroll
      for (int n = 0; n < 4; ++n)
        acc[m][n] = __builtin_amdgcn_mfma_f32_16x16x32_bf16(a[m], b[n], acc[m][n], 0, 0, 0);
    __builtin_amdgcn_s_setprio(0);

    if (t + 1 < NT) {
      // my stage(t+1) landed; barrier => ALL waves' stage(t+1) landed
      if (st) { asm volatile("s_waitcnt vmcnt(6)" ::: "memory"); }
      else    { asm volatile("s_waitcnt vmcnt(0)" ::: "memory"); }
      __builtin_amdgcn_s_barrier();
      asm volatile("" ::: "memory");
      const int bnext = (bcur + 1 == 3) ? 0 : bcur + 1;
      const __bf16* pA = &sA[bnext * 8192 + offA];
      const __bf16* pB = &sB[bnext * 4096 + offB];
#pragma unroll
      for (int m = 0; m < 8; ++m) a[m] = *(const bf16x8*)(pA + m * 512);
#pragma unroll
      for (int n = 0; n < 4; ++n) b[n] = *(const bf16x8*)(pB + n * 512);
    }
    bcur = (bcur + 1 == 3) ? 0 : bcur + 1;
  }
#undef STAGE

  // epilogue (wave-tile 128x64)
#pragma unroll
  for (int n = 0; n < 4; ++n) {
    const int col = bn + wn * 64 + n * 16 + lq;
    const float bv = BIAS ? bias[col] : 0.0f;
#pragma unroll
    for (int m = 0; m < 8; ++m)
#pragma unroll
      for (int r = 0; r < 4; ++r) {
        const int row = bm + wm * 128 + m * 16 + lg * 4 + r;
        C[(size_t)row * ldc + col] = (OUT_T)(acc[m][n][r] + bv);
      }
  }
}

// ======== gemm_sq: BM=BN=128 BK=32, 4 waves, wave-tile 64x64 ========
// acc[4][4]=64 regs fits (256,3). 48KB triple-buffer, lead-2 counted
// vmcnt(4); grid 512 = full machine, single round.
template<int BIAS, typename OUT_T>
__global__ __launch_bounds__(256, 3) void gemm_sq(
    const __bf16* __restrict__ A, int lda,
    const __bf16* __restrict__ B, int ldb,
    const float* __restrict__ bias,
    OUT_T* __restrict__ C, int ldc, int K, int nby)
{
  __shared__ __bf16 sA[3 * 128 * 32];   // 24 KB
  __shared__ __bf16 sB[3 * 128 * 32];   // 24 KB
  const int tid = threadIdx.x;
  const int w = tid >> 6, lane = tid & 63;
  const int lq = lane & 15, lg = lane >> 4;
  const int wm = w >> 1, wn = w & 1;

  const int nwg = gridDim.x, cpx = nwg >> 3, bid = blockIdx.x;
  const int wgid = (bid & 7) * cpx + (bid >> 3);
  const int by = wgid % nby, bx = wgid / nby;
  const int bm = by * 128, bn = bx * 128;

  const int srow = tid >> 2;
  const int scol = ((tid & 3) ^ ((srow >> 1) & 3)) * 8;
  const __bf16* gA = A + (size_t)(bm + srow) * lda + scol;
  const __bf16* gB = B + (size_t)(bn + srow) * ldb + scol;
  const int w16 = w * 16;
  const int NT = K >> 5;

#define STAGE(t, bf) {                                                    \
    const __bf16* sa_ = gA + (size_t)(t) * 32;                            \
    gld_lds16(sa_,                     &sA[(bf) * 4096 + (w16) * 32]);    \
    gld_lds16(sa_ + (size_t)64 * lda,  &sA[(bf) * 4096 + (64 + w16) * 32]); \
    const __bf16* sb_ = gB + (size_t)(t) * 32;                            \
    gld_lds16(sb_,                     &sB[(bf) * 4096 + (w16) * 32]);    \
    gld_lds16(sb_ + (size_t)64 * ldb,  &sB[(bf) * 4096 + (64 + w16) * 32]); }

  f32x4 acc[4][4] = {};

  const int colo = (lg ^ ((lq >> 1) & 3)) * 8;
  const int offA = (wm * 64 + lq) * 32 + colo;
  const int offB = (wn * 64 + lq) * 32 + colo;

  STAGE(0, 0); STAGE(1, 1);
  asm volatile("s_waitcnt vmcnt(4)" ::: "memory");   // tile0's 4 loads landed
  __builtin_amdgcn_s_barrier();
  asm volatile("" ::: "memory");

  bf16x8 a[4], b[4];
  {
    const __bf16* pA = &sA[offA];
    const __bf16* pB = &sB[offB];
#pragma unroll
    for (int m = 0; m < 4; ++m) a[m] = *(const bf16x8*)(pA + m * 512);
#pragma unroll
    for (int n = 0; n < 4; ++n) b[n] = *(const bf16x8*)(pB + n * 512);
  }

  int bcur = 0;
  for (int t = 0; t < NT; ++t) {
    int bstg = bcur + 2; if (bstg >= 3) bstg -= 3;
    const bool st = (t + 2) < NT;
    if (st) STAGE(t + 2, bstg);

    asm volatile("s_waitcnt lgkmcnt(0)" ::: "memory");
    __builtin_amdgcn_sched_barrier(0);
    __builtin_amdgcn_s_setprio(1);
#pragma unroll
    for (int m = 0; m < 4; ++m)
#pragma unroll
      for (int n = 0; n < 4; ++n)
        acc[m][n] = __builtin_amdgcn_mfma_f32_16x16x32_bf16(a[m], b[n], acc[m][n], 0, 0, 0);
    __builtin_amdgcn_s_setprio(0);

    if (t + 1 < NT) {
      if (st) { asm volatile("s_waitcnt vmcnt(4)" ::: "memory"); }
      else    { asm volatile("s_waitcnt vmcnt(0)" ::: "memory"); }
      __builtin_amdgcn_s_barrier();
      asm volatile("" ::: "memory");
      const int bnext = (bcur + 1 == 3) ? 0 : bcur + 1;
      const __bf16* pA = &sA[bnext * 4096 + offA];
      const __bf16* pB = &sB[bnext * 4096 + offB];
#pragma unroll
      for (int m = 0; m < 4; ++m) a[m] = *(const bf16x8*)(pA + m * 512);
#pragma unroll
      for (int n = 0; n < 4; ++n) b[n] = *(const bf16x8*)(pB + n * 512);
    }
    bcur = (bcur + 1 == 3) ? 0 : bcur + 1;
  }
#undef STAGE

#pragma unroll
  for (int n = 0; n < 4; ++n) {
    const int col = bn + wn * 64 + n * 16 + lq;
    const float bv = BIAS ? bias[col] : 0.0f;
#pragma unroll
    for (int m = 0; m < 4; ++m)
#pragma unroll
      for (int r = 0; r < 4; ++r) {
        const int row = bm + wm * 64 + m * 16 + lg * 4 + r;
        C[(size_t)row * ldc + col] = (OUT_T)(acc[m][n][r] + bv);
      }
  }
}

// ---------------- pack: RoPE(Q,K) -> Qp/Kp [bh][s][d]; V -> Vt [bh][d][s] ----------------
__global__ __launch_bounds__(256) void pack_kernel(const __bf16* __restrict__ qkv,
                                                   const float* __restrict__ cosb,
                                                   const float* __restrict__ sinb,
                                                   __bf16* __restrict__ Qp,
                                                   __bf16* __restrict__ Kp,
                                                   __bf16* __restrict__ Vt)
{
  __shared__ __bf16 tile[64][136];
  const int bh = blockIdx.y, b = bh >> 4, h = bh & 15;
  const int s0 = blockIdx.x * 64;
  const int tid = threadIdx.x;
  const int j0 = (tid & 7) * 8;
  const float qsc = 0.08838834764831845f;  // 1/sqrt(128)

#pragma unroll
  for (int it = 0; it < 2; ++it) {
    const int r = (tid >> 3) + it * 32;
    const int s = s0 + r;
    const size_t t = (size_t)b * SEQ + s;
    float cc[8], ss[8];
    *(float4*)&cc[0] = *(const float4*)&cosb[t * 64 + j0];
    *(float4*)&cc[4] = *(const float4*)&cosb[t * 64 + j0 + 4];
    *(float4*)&ss[0] = *(const float4*)&sinb[t * 64 + j0];
    *(float4*)&ss[4] = *(const float4*)&sinb[t * 64 + j0 + 4];
    const __bf16* src = qkv + t * QKVW + h * DIM;
    const bf16x8 q1 = *(const bf16x8*)(src + j0);
    const bf16x8 q2 = *(const bf16x8*)(src + 64 + j0);
    const bf16x8 k1 = *(const bf16x8*)(src + HIDN + j0);
    const bf16x8 k2 = *(const bf16x8*)(src + HIDN + 64 + j0);
    bf16x8 oq1, oq2, ok1, ok2;
#pragma unroll
    for (int jj = 0; jj < 8; ++jj) {
      const float c = cc[jj], sn = ss[jj];
      const float a1 = (float)q1[jj], a2 = (float)q2[jj];
      const float b1 = (float)k1[jj], b2 = (float)k2[jj];
      oq1[jj] = (__bf16)((a1 * c - a2 * sn) * qsc);
      oq2[jj] = (__bf16)((a2 * c + a1 * sn) * qsc);
      ok1[jj] = (__bf16)(b1 * c - b2 * sn);
      ok2[jj] = (__bf16)(b2 * c + b1 * sn);
    }
    __bf16* dq = Qp + ((size_t)bh * SEQ + s) * DIM + j0;
    __bf16* dk = Kp + ((size_t)bh * SEQ + s) * DIM + j0;
    *(bf16x8*)dq = oq1; *(bf16x8*)(dq + 64) = oq2;
    *(bf16x8*)dk = ok1; *(bf16x8*)(dk + 64) = ok2;
  }

#pragma unroll
  for (int i = 0; i < 4; ++i) {
    const int r = (tid >> 4) + i * 16;
    const int c = (tid & 15) * 8;
    *(bf16x8*)&tile[r][c] =
        *(const bf16x8*)&qkv[((size_t)b * SEQ + s0 + r) * QKVW + 2 * HIDN + h * DIM + c];
  }
  __syncthreads();
#pragma unroll
  for (int i = 0; i < 4; ++i) {
    const int d = (tid >> 3) + i * 32;
    const int scc = (tid & 7) * 8;
    bf16x8 v;
#pragma unroll
    for (int jj = 0; jj < 8; ++jj) v[jj] = tile[scc + jj][d];
    *(bf16x8*)&Vt[((size_t)bh * DIM + d) * SEQ + s0 + scc] = v;
  }
}

// ---------------- causal flash attention v3 (unchanged) ----------------
__global__ __launch_bounds__(256, 2) void attn_kernel(const __bf16* __restrict__ Qp,
                                                      const __bf16* __restrict__ Kp,
                                                      const __bf16* __restrict__ Vt,
                                                      __bf16* __restrict__ O)
{
  __shared__ __bf16 sK[2][64 * 128];   // 32 KB
  __shared__ __bf16 sV[2][128 * 64];   // 32 KB
  __shared__ __bf16 sP[4][32 * 64];    // 16 KB (XOR-swizzled)
  const int w = threadIdx.x >> 6, lane = threadIdx.x & 63;
  const int lq = lane & 15, lg = lane >> 4;
  const int bh = blockIdx.y, b = bh >> 4, h = bh & 15;
  const int qb = ((int)blockIdx.x + bh) & 7;
  const int q0 = qb * 128 + w * 32;
  const int NTb = 2 * qb + 2;
  const int kend = q0 + 32;

  const __bf16* Qh = Qp + (size_t)bh * SEQ * DIM;
  const __bf16* Kh = Kp + (size_t)bh * SEQ * DIM;
  const __bf16* Vh = Vt + (size_t)bh * DIM * SEQ;

  const int krow = lane >> 4;
  const int kgr  = lane & 15;
  const int vrow = lane >> 3;
  const int vgr  = lane & 7;
  const __bf16* Vsrc = Vh + (size_t)(w * 32 + vrow) * SEQ + (vgr ^ vrow) * 8;

  auto ASTAGE = [&](int ktn, int p) {
#pragma unroll
    for (int i = 0; i < 4; ++i) {
      const int rb = w * 16 + i * 4;
      gld_lds16(Kh + (size_t)(ktn + rb + krow) * DIM + (kgr ^ (i * 4 + krow)) * 8,
                &sK[p][rb * DIM]);
    }
#pragma unroll
    for (int i = 0; i < 4; ++i) {
      gld_lds16(Vsrc + (size_t)i * 8 * SEQ + ktn, &sV[p][(w * 32 + i * 8) * 64]);
    }
  };

  bf16x8 aq[2][4];
#pragma unroll
  for (int m = 0; m < 2; ++m)
#pragma unroll
    for (int kk = 0; kk < 4; ++kk)
      aq[m][kk] = *(const bf16x8*)(Qh + (size_t)(q0 + m * 16 + lq) * DIM + kk * 32 + lg * 8);

  f32x4 accO[2][8] = {};
  float mrow[2][4], lrow[2][4];
#pragma unroll
  for (int m = 0; m < 2; ++m)
#pragma unroll
    for (int r = 0; r < 4; ++r) { mrow[m][r] = -1e30f; lrow[m][r] = 0.0f; }

  ASTAGE(0, 0);
  asm volatile("s_waitcnt vmcnt(0)" ::: "memory");
  __builtin_amdgcn_s_barrier();

  int p = 0;
  for (int t = 0; t < NTb; ++t) {
    const int kt = t * 64;
    if (t + 1 < NTb) ASTAGE(kt + 64, p ^ 1);

    if (kt < kend) {
      f32x4 s[2][4] = {};
#pragma unroll
      for (int n = 0; n < 4; ++n) {
        const int rowb = (n * 16 + lq) * DIM;
#pragma unroll
        for (int kk = 0; kk < 4; ++kk) {
          const bf16x8 bk = *(const bf16x8*)&sK[p][rowb + ((4 * kk + lg) ^ lq) * 8];
#pragma unroll
          for (int m = 0; m < 2; ++m)
            s[m][n] = __builtin_amdgcn_mfma_f32_16x16x32_bf16(aq[m][kk], bk, s[m][n], 0, 0, 0);
        }
      }
      if (kt + 63 > q0) {
#pragma unroll
        for (int n = 0; n < 4; ++n) {
          const int kpos = kt + n * 16 + lq;
#pragma unroll
          for (int m = 0; m < 2; ++m)
#pragma unroll
            for (int r = 0; r < 4; ++r)
              if (kpos > q0 + m * 16 + lg * 4 + r) s[m][n][r] = -1e30f;
        }
      }
#pragma unroll
      for (int m = 0; m < 2; ++m) {
#pragma unroll
        for (int r = 0; r < 4; ++r) {
          float mx = fmaxf(fmaxf(s[m][0][r], s[m][1][r]), fmaxf(s[m][2][r], s[m][3][r]));
          mx = fmaxf(mx, __shfl_xor(mx, 1));
          mx = fmaxf(mx, __shfl_xor(mx, 2));
          mx = fmaxf(mx, __shfl_xor(mx, 4));
          mx = fmaxf(mx, __shfl_xor(mx, 8));
          const float mnew = fmaxf(mrow[m][r], mx);
          const float alpha = __expf(mrow[m][r] - mnew);
          mrow[m][r] = mnew;
          float rs = 0.0f;
#pragma unroll
          for (int n = 0; n < 4; ++n) {
            const float pv = __expf(s[m][n][r] - mnew);
            s[m][n][r] = pv;
            rs += pv;
          }
          rs += __shfl_xor(rs, 1); rs += __shfl_xor(rs, 2);
          rs += __shfl_xor(rs, 4); rs += __shfl_xor(rs, 8);
          lrow[m][r] = lrow[m][r] * alpha + rs;
#pragma unroll
          for (int f = 0; f < 8; ++f) accO[m][f][r] *= alpha;
        }
      }
#pragma unroll
      for (int m = 0; m < 2; ++m)
#pragma unroll
        for (int n = 0; n < 4; ++n)
#pragma unroll
          for (int r = 0; r < 4; ++r) {
            const int prow = m * 16 + lg * 4 + r;
            const int cb = (n * 16 + lq) * 2;
            const int addr = prow * 128 + (((cb >> 4) ^ (prow & 7)) << 4) + (cb & 15);
            *(__bf16*)((char*)&sP[w][0] + addr) = (__bf16)s[m][n][r];
          }
      asm volatile("s_waitcnt lgkmcnt(0)" ::: "memory");
#pragma unroll
      for (int kk2 = 0; kk2 < 2; ++kk2) {
        bf16x8 ap[2];
#pragma unroll
        for (int m = 0; m < 2; ++m) {
          const int prow = m * 16 + lq;
          ap[m] = *(const bf16x8*)((char*)&sP[w][0] +
                   prow * 128 + (((4 * kk2 + lg) ^ (lq & 7)) << 4));
        }
#pragma unroll
        for (int f = 0; f < 8; ++f) {
          const bf16x8 bv = *(const bf16x8*)&sV[p][(f * 16 + lq) * 64 +
                                                   ((4 * kk2 + lg) ^ (lq & 7)) * 8];
#pragma unroll
          for (int m = 0; m < 2; ++m)
            accO[m][f] = __builtin_amdgcn_mfma_f32_16x16x32_bf16(ap[m], bv, accO[m][f], 0, 0, 0);
        }
      }
    }
    asm volatile("s_waitcnt vmcnt(0)" ::: "memory");
    __builtin_amdgcn_s_barrier();
    p ^= 1;
  }

#pragma unroll
  for (int m = 0; m < 2; ++m)
#pragma unroll
    for (int f = 0; f < 8; ++f)
#pragma unroll
      for (int r = 0; r < 4; ++r) {
        const float v = accO[m][f][r] / lrow[m][r];
        O[((size_t)b * SEQ + q0 + m * 16 + lg * 4 + r) * HIDN + h * DIM + f * 16 + lq] = (__bf16)v;
      }
}

// ---------------- launch ----------------
extern "C" void kernel_launch(void* const* d_in, const int* in_sizes, int n_in,
                              void* d_out, int out_size, void* d_ws, size_t ws_size,
                              hipStream_t stream)
{
  const float* hidden = (const float*)d_in[0];
  const float* cosb   = (const float*)d_in[1];
  const float* sinb   = (const float*)d_in[2];
  const float* w_attn = (const float*)d_in[3];
  const float* b_attn = (const float*)d_in[4];
  const float* w_proj = (const float*)d_in[5];

  char* ws = (char*)d_ws;
  __bf16* hid_bf   = (__bf16*)(ws);                 // [0, 16M)
  __bf16* wattn_bf = (__bf16*)(ws + 16777216);      // [16M, 40M)
  __bf16* wproj_bf = (__bf16*)(ws + 41943040);      // [40M, 48M)
  __bf16* qkv      = (__bf16*)(ws + 50331648);      // [48M, 96M)
  __bf16* Qp       = (__bf16*)(ws);                 // [0, 16M)  (reuse, post-GEMM1)
  __bf16* Kp       = (__bf16*)(ws + 16777216);      // [16M, 32M)
  __bf16* Vt       = (__bf16*)(ws + 100663296);     // [96M, 112M)
  __bf16* Obuf     = (__bf16*)(ws + 117440512);     // [112M, 128M)
  float* out = (float*)d_out;

  f2b_all<<<24576, 256, 0, stream>>>(hidden, hid_bf, w_attn, wattn_bf, w_proj, wproj_bf);

  // qkv = hidden @ w_attn^T + b   (M=4096, N=6144, K=2048): 16x48 = 768 blocks
  gemm_wide<1, __bf16><<<768, 256, 0, stream>>>(
      hid_bf, HIDN, wattn_bf, HIDN, b_attn, qkv, QKVW, HIDN, 16);

  pack_kernel<<<dim3(16, 64), 256, 0, stream>>>(qkv, cosb, sinb, Qp, Kp, Vt);
  attn_kernel<<<dim3(8, 64), 256, 0, stream>>>(Qp, Kp, Vt, Obuf);

  // out = O @ w_proj^T   (M=4096, N=2048, K=2048): 32x16 = 512 blocks, f32 out
  gemm_sq<0, float><<<512, 256, 0, stream>>>(
      Obuf, HIDN, wproj_bf, HIDN, nullptr, out, HIDN, HIDN, 32);
}

// Round 15
// 269.906 us; speedup vs baseline: 2.0863x; 1.0004x over previous
//
#include <hip/hip_runtime.h>

typedef __bf16 bf16x8 __attribute__((ext_vector_type(8)));
typedef __bf16 bf16x4 __attribute__((ext_vector_type(4)));
typedef float  f32x4  __attribute__((ext_vector_type(4)));

#define T_TOT 4096
#define SEQ   1024
#define BATCH 4
#define HEADS 16
#define DIM   128
#define HIDN  2048
#define QKVW  6144

__device__ __forceinline__ void gld_lds16(const void* g, void* l) {
  __builtin_amdgcn_global_load_lds(
      (const __attribute__((address_space(1))) unsigned int*)g,
      (__attribute__((address_space(3))) unsigned int*)l, 16, 0, 0);
}

// ---------------- merged f32 -> bf16 conversions (one launch) ----------------
__global__ void f2b_all(const float* __restrict__ h,  __bf16* __restrict__ oh,
                        const float* __restrict__ wa, __bf16* __restrict__ owa,
                        const float* __restrict__ wp, __bf16* __restrict__ owp)
{
  const int bid = blockIdx.x;
  const float* in;
  __bf16* out;
  int base;
  if (bid < 8192)       { in = h;  out = oh;  base = bid; }
  else if (bid < 20480) { in = wa; out = owa; base = bid - 8192; }
  else                  { in = wp; out = owp; base = bid - 20480; }
  const int i = (base * 256 + threadIdx.x) * 4;
  const float4 v = *(const float4*)(in + i);
  bf16x4 o;
  o[0] = (__bf16)v.x; o[1] = (__bf16)v.y; o[2] = (__bf16)v.z; o[3] = (__bf16)v.w;
  *(bf16x4*)(out + i) = o;
}

// ======== gemm_wide (PROVEN round-11, 127us): BM=256 BN=128 BK=32 ========
// 4 waves, wave-tile 128x64 (needs ~200 unified regs -> MAX 2 blocks/CU;
// (256,3) spills acc to scratch, round-13 lesson). 72KB triple-buffer,
// lead-2 counted vmcnt(6), ONE barrier/tile, frag prefetch after barrier.
template<int BIAS, typename OUT_T>
__global__ __launch_bounds__(256, 2) void gemm_wide(
    const __bf16* __restrict__ A, int lda,
    const __bf16* __restrict__ B, int ldb,
    const float* __restrict__ bias,
    OUT_T* __restrict__ C, int ldc, int K, int nby)
{
  __shared__ __bf16 sA[3 * 256 * 32];   // 48 KB
  __shared__ __bf16 sB[3 * 128 * 32];   // 24 KB
  const int tid = threadIdx.x;
  const int w = tid >> 6, lane = tid & 63;
  const int lq = lane & 15, lg = lane >> 4;
  const int wm = w >> 1, wn = w & 1;

  // bijective XCD swizzle (gridDim.x % 8 == 0); M-major chunks per XCD
  const int nwg = gridDim.x, cpx = nwg >> 3, bid = blockIdx.x;
  const int wgid = (bid & 7) * cpx + (bid >> 3);
  const int by = wgid % nby, bx = wgid / nby;
  const int bm = by * 256, bn = bx * 128;

  // staging: one issue = 256 thr x 16B = 64 rows x 64B
  const int srow = tid >> 2;                             // 0..63
  const int scol = ((tid & 3) ^ ((srow >> 1) & 3)) * 8;  // pre-swizzled col
  const __bf16* gA = A + (size_t)(bm + srow) * lda + scol;
  const __bf16* gB = B + (size_t)(bn + srow) * ldb + scol;
  __bf16* dA = &sA[w * 512];
  __bf16* dB = &sB[w * 512];

  const int NT = K >> 5;

#define STAGE(t, bf) {                                               \
    const __bf16* sa_ = gA + (size_t)(t) * 32;                       \
    gld_lds16(sa_,                      dA + (bf) * 8192);           \
    gld_lds16(sa_ + (size_t) 64 * lda,  dA + (bf) * 8192 + 2048);    \
    gld_lds16(sa_ + (size_t)128 * lda,  dA + (bf) * 8192 + 4096);    \
    gld_lds16(sa_ + (size_t)192 * lda,  dA + (bf) * 8192 + 6144);    \
    const __bf16* sb_ = gB + (size_t)(t) * 32;                       \
    gld_lds16(sb_,                      dB + (bf) * 4096);           \
    gld_lds16(sb_ + (size_t) 64 * ldb,  dB + (bf) * 4096 + 2048); }

  f32x4 acc[8][4] = {};

  // ds_read: stored granule = lg ^ ((row>>1)&3); row = base16 + lq
  const int colo = (lg ^ ((lq >> 1) & 3)) * 8;
  const int offA = (wm * 128 + lq) * 32 + colo;
  const int offB = (wn * 64 + lq) * 32 + colo;

  STAGE(0, 0); STAGE(1, 1);
  asm volatile("s_waitcnt vmcnt(6)" ::: "memory");   // tile0 landed
  __builtin_amdgcn_s_barrier();
  asm volatile("" ::: "memory");

  bf16x8 a[8], b[4];
  {
    const __bf16* pA = &sA[offA];
    const __bf16* pB = &sB[offB];
#pragma unroll
    for (int m = 0; m < 8; ++m) a[m] = *(const bf16x8*)(pA + m * 512);
#pragma unroll
    for (int n = 0; n < 4; ++n) b[n] = *(const bf16x8*)(pB + n * 512);
  }

  int bcur = 0;
  for (int t = 0; t < NT; ++t) {
    int bstg = bcur + 2; if (bstg >= 3) bstg -= 3;
    const bool st = (t + 2) < NT;
    if (st) STAGE(t + 2, bstg);   // buf(t-1): readers drained at end-of-(t-1) barrier

    asm volatile("s_waitcnt lgkmcnt(0)" ::: "memory");
    __builtin_amdgcn_sched_barrier(0);
    __builtin_amdgcn_s_setprio(1);
#pragma unroll
    for (int m = 0; m < 8; ++m)
#pragma unroll
      for (int n = 0; n < 4; ++n)
        acc[m][n] = __builtin_amdgcn_mfma_f32_16x16x32_bf16(a[m], b[n], acc[m][n], 0, 0, 0);
    __builtin_amdgcn_s_setprio(0);

    if (t + 1 < NT) {
      // my stage(t+1) landed; barrier => ALL waves' stage(t+1) landed
      if (st) { asm volatile("s_waitcnt vmcnt(6)" ::: "memory"); }
      else    { asm volatile("s_waitcnt vmcnt(0)" ::: "memory"); }
      __builtin_amdgcn_s_barrier();
      asm volatile("" ::: "memory");
      const int bnext = (bcur + 1 == 3) ? 0 : bcur + 1;
      const __bf16* pA = &sA[bnext * 8192 + offA];
      const __bf16* pB = &sB[bnext * 4096 + offB];
#pragma unroll
      for (int m = 0; m < 8; ++m) a[m] = *(const bf16x8*)(pA + m * 512);
#pragma unroll
      for (int n = 0; n < 4; ++n) b[n] = *(const bf16x8*)(pB + n * 512);
    }
    bcur = (bcur + 1 == 3) ? 0 : bcur + 1;
  }
#undef STAGE

  // epilogue (wave-tile 128x64)
#pragma unroll
  for (int n = 0; n < 4; ++n) {
    const int col = bn + wn * 64 + n * 16 + lq;
    const float bv = BIAS ? bias[col] : 0.0f;
#pragma unroll
    for (int m = 0; m < 8; ++m)
#pragma unroll
      for (int r = 0; r < 4; ++r) {
        const int row = bm + wm * 128 + m * 16 + lg * 4 + r;
        C[(size_t)row * ldc + col] = (OUT_T)(acc[m][n][r] + bv);
      }
  }
}

// ======== gemm_sq: BM=BN=128 BK=32, 4 waves, wave-tile 64x64 ========
// acc[4][4]=64 regs fits (256,3). 48KB triple-buffer, lead-2 counted
// vmcnt(4); grid 512 = full machine, single round.
template<int BIAS, typename OUT_T>
__global__ __launch_bounds__(256, 3) void gemm_sq(
    const __bf16* __restrict__ A, int lda,
    const __bf16* __restrict__ B, int ldb,
    const float* __restrict__ bias,
    OUT_T* __restrict__ C, int ldc, int K, int nby)
{
  __shared__ __bf16 sA[3 * 128 * 32];   // 24 KB
  __shared__ __bf16 sB[3 * 128 * 32];   // 24 KB
  const int tid = threadIdx.x;
  const int w = tid >> 6, lane = tid & 63;
  const int lq = lane & 15, lg = lane >> 4;
  const int wm = w >> 1, wn = w & 1;

  const int nwg = gridDim.x, cpx = nwg >> 3, bid = blockIdx.x;
  const int wgid = (bid & 7) * cpx + (bid >> 3);
  const int by = wgid % nby, bx = wgid / nby;
  const int bm = by * 128, bn = bx * 128;

  const int srow = tid >> 2;
  const int scol = ((tid & 3) ^ ((srow >> 1) & 3)) * 8;
  const __bf16* gA = A + (size_t)(bm + srow) * lda + scol;
  const __bf16* gB = B + (size_t)(bn + srow) * ldb + scol;
  const int w16 = w * 16;
  const int NT = K >> 5;

#define STAGE(t, bf) {                                                    \
    const __bf16* sa_ = gA + (size_t)(t) * 32;                            \
    gld_lds16(sa_,                     &sA[(bf) * 4096 + (w16) * 32]);    \
    gld_lds16(sa_ + (size_t)64 * lda,  &sA[(bf) * 4096 + (64 + w16) * 32]); \
    const __bf16* sb_ = gB + (size_t)(t) * 32;                            \
    gld_lds16(sb_,                     &sB[(bf) * 4096 + (w16) * 32]);    \
    gld_lds16(sb_ + (size_t)64 * ldb,  &sB[(bf) * 4096 + (64 + w16) * 32]); }

  f32x4 acc[4][4] = {};

  const int colo = (lg ^ ((lq >> 1) & 3)) * 8;
  const int offA = (wm * 64 + lq) * 32 + colo;
  const int offB = (wn * 64 + lq) * 32 + colo;

  STAGE(0, 0); STAGE(1, 1);
  asm volatile("s_waitcnt vmcnt(4)" ::: "memory");   // tile0's 4 loads landed
  __builtin_amdgcn_s_barrier();
  asm volatile("" ::: "memory");

  bf16x8 a[4], b[4];
  {
    const __bf16* pA = &sA[offA];
    const __bf16* pB = &sB[offB];
#pragma unroll
    for (int m = 0; m < 4; ++m) a[m] = *(const bf16x8*)(pA + m * 512);
#pragma unroll
    for (int n = 0; n < 4; ++n) b[n] = *(const bf16x8*)(pB + n * 512);
  }

  int bcur = 0;
  for (int t = 0; t < NT; ++t) {
    int bstg = bcur + 2; if (bstg >= 3) bstg -= 3;
    const bool st = (t + 2) < NT;
    if (st) STAGE(t + 2, bstg);

    asm volatile("s_waitcnt lgkmcnt(0)" ::: "memory");
    __builtin_amdgcn_sched_barrier(0);
    __builtin_amdgcn_s_setprio(1);
#pragma unroll
    for (int m = 0; m < 4; ++m)
#pragma unroll
      for (int n = 0; n < 4; ++n)
        acc[m][n] = __builtin_amdgcn_mfma_f32_16x16x32_bf16(a[m], b[n], acc[m][n], 0, 0, 0);
    __builtin_amdgcn_s_setprio(0);

    if (t + 1 < NT) {
      if (st) { asm volatile("s_waitcnt vmcnt(4)" ::: "memory"); }
      else    { asm volatile("s_waitcnt vmcnt(0)" ::: "memory"); }
      __builtin_amdgcn_s_barrier();
      asm volatile("" ::: "memory");
      const int bnext = (bcur + 1 == 3) ? 0 : bcur + 1;
      const __bf16* pA = &sA[bnext * 4096 + offA];
      const __bf16* pB = &sB[bnext * 4096 + offB];
#pragma unroll
      for (int m = 0; m < 4; ++m) a[m] = *(const bf16x8*)(pA + m * 512);
#pragma unroll
      for (int n = 0; n < 4; ++n) b[n] = *(const bf16x8*)(pB + n * 512);
    }
    bcur = (bcur + 1 == 3) ? 0 : bcur + 1;
  }
#undef STAGE

#pragma unroll
  for (int n = 0; n < 4; ++n) {
    const int col = bn + wn * 64 + n * 16 + lq;
    const float bv = BIAS ? bias[col] : 0.0f;
#pragma unroll
    for (int m = 0; m < 4; ++m)
#pragma unroll
      for (int r = 0; r < 4; ++r) {
        const int row = bm + wm * 64 + m * 16 + lg * 4 + r;
        C[(size_t)row * ldc + col] = (OUT_T)(acc[m][n][r] + bv);
      }
  }
}

// ---------------- pack: RoPE(Q,K) -> Qp/Kp [bh][s][d]; V -> Vt [bh][d][s] ----------------
__global__ __launch_bounds__(256) void pack_kernel(const __bf16* __restrict__ qkv,
                                                   const float* __restrict__ cosb,
                                                   const float* __restrict__ sinb,
                                                   __bf16* __restrict__ Qp,
                                                   __bf16* __restrict__ Kp,
                                                   __bf16* __restrict__ Vt)
{
  __shared__ __bf16 tile[64][136];
  const int bh = blockIdx.y, b = bh >> 4, h = bh & 15;
  const int s0 = blockIdx.x * 64;
  const int tid = threadIdx.x;
  const int j0 = (tid & 7) * 8;
  const float qsc = 0.08838834764831845f;  // 1/sqrt(128)

#pragma unroll
  for (int it = 0; it < 2; ++it) {
    const int r = (tid >> 3) + it * 32;
    const int s = s0 + r;
    const size_t t = (size_t)b * SEQ + s;
    float cc[8], ss[8];
    *(float4*)&cc[0] = *(const float4*)&cosb[t * 64 + j0];
    *(float4*)&cc[4] = *(const float4*)&cosb[t * 64 + j0 + 4];
    *(float4*)&ss[0] = *(const float4*)&sinb[t * 64 + j0];
    *(float4*)&ss[4] = *(const float4*)&sinb[t * 64 + j0 + 4];
    const __bf16* src = qkv + t * QKVW + h * DIM;
    const bf16x8 q1 = *(const bf16x8*)(src + j0);
    const bf16x8 q2 = *(const bf16x8*)(src + 64 + j0);
    const bf16x8 k1 = *(const bf16x8*)(src + HIDN + j0);
    const bf16x8 k2 = *(const bf16x8*)(src + HIDN + 64 + j0);
    bf16x8 oq1, oq2, ok1, ok2;
#pragma unroll
    for (int jj = 0; jj < 8; ++jj) {
      const float c = cc[jj], sn = ss[jj];
      const float a1 = (float)q1[jj], a2 = (float)q2[jj];
      const float b1 = (float)k1[jj], b2 = (float)k2[jj];
      oq1[jj] = (__bf16)((a1 * c - a2 * sn) * qsc);
      oq2[jj] = (__bf16)((a2 * c + a1 * sn) * qsc);
      ok1[jj] = (__bf16)(b1 * c - b2 * sn);
      ok2[jj] = (__bf16)(b2 * c + b1 * sn);
    }
    __bf16* dq = Qp + ((size_t)bh * SEQ + s) * DIM + j0;
    __bf16* dk = Kp + ((size_t)bh * SEQ + s) * DIM + j0;
    *(bf16x8*)dq = oq1; *(bf16x8*)(dq + 64) = oq2;
    *(bf16x8*)dk = ok1; *(bf16x8*)(dk + 64) = ok2;
  }

#pragma unroll
  for (int i = 0; i < 4; ++i) {
    const int r = (tid >> 4) + i * 16;
    const int c = (tid & 15) * 8;
    *(bf16x8*)&tile[r][c] =
        *(const bf16x8*)&qkv[((size_t)b * SEQ + s0 + r) * QKVW + 2 * HIDN + h * DIM + c];
  }
  __syncthreads();
#pragma unroll
  for (int i = 0; i < 4; ++i) {
    const int d = (tid >> 3) + i * 32;
    const int scc = (tid & 7) * 8;
    bf16x8 v;
#pragma unroll
    for (int jj = 0; jj < 8; ++jj) v[jj] = tile[scc + jj][d];
    *(bf16x8*)&Vt[((size_t)bh * DIM + d) * SEQ + s0 + scc] = v;
  }
}

// ---------------- causal flash attention v3 (unchanged) ----------------
__global__ __launch_bounds__(256, 2) void attn_kernel(const __bf16* __restrict__ Qp,
                                                      const __bf16* __restrict__ Kp,
                                                      const __bf16* __restrict__ Vt,
                                                      __bf16* __restrict__ O)
{
  __shared__ __bf16 sK[2][64 * 128];   // 32 KB
  __shared__ __bf16 sV[2][128 * 64];   // 32 KB
  __shared__ __bf16 sP[4][32 * 64];    // 16 KB (XOR-swizzled)
  const int w = threadIdx.x >> 6, lane = threadIdx.x & 63;
  const int lq = lane & 15, lg = lane >> 4;
  const int bh = blockIdx.y, b = bh >> 4, h = bh & 15;
  const int qb = ((int)blockIdx.x + bh) & 7;
  const int q0 = qb * 128 + w * 32;
  const int NTb = 2 * qb + 2;
  const int kend = q0 + 32;

  const __bf16* Qh = Qp + (size_t)bh * SEQ * DIM;
  const __bf16* Kh = Kp + (size_t)bh * SEQ * DIM;
  const __bf16* Vh = Vt + (size_t)bh * DIM * SEQ;

  const int krow = lane >> 4;
  const int kgr  = lane & 15;
  const int vrow = lane >> 3;
  const int vgr  = lane & 7;
  const __bf16* Vsrc = Vh + (size_t)(w * 32 + vrow) * SEQ + (vgr ^ vrow) * 8;

  auto ASTAGE = [&](int ktn, int p) {
#pragma unroll
    for (int i = 0; i < 4; ++i) {
      const int rb = w * 16 + i * 4;
      gld_lds16(Kh + (size_t)(ktn + rb + krow) * DIM + (kgr ^ (i * 4 + krow)) * 8,
                &sK[p][rb * DIM]);
    }
#pragma unroll
    for (int i = 0; i < 4; ++i) {
      gld_lds16(Vsrc + (size_t)i * 8 * SEQ + ktn, &sV[p][(w * 32 + i * 8) * 64]);
    }
  };

  bf16x8 aq[2][4];
#pragma unroll
  for (int m = 0; m < 2; ++m)
#pragma unroll
    for (int kk = 0; kk < 4; ++kk)
      aq[m][kk] = *(const bf16x8*)(Qh + (size_t)(q0 + m * 16 + lq) * DIM + kk * 32 + lg * 8);

  f32x4 accO[2][8] = {};
  float mrow[2][4], lrow[2][4];
#pragma unroll
  for (int m = 0; m < 2; ++m)
#pragma unroll
    for (int r = 0; r < 4; ++r) { mrow[m][r] = -1e30f; lrow[m][r] = 0.0f; }

  ASTAGE(0, 0);
  asm volatile("s_waitcnt vmcnt(0)" ::: "memory");
  __builtin_amdgcn_s_barrier();

  int p = 0;
  for (int t = 0; t < NTb; ++t) {
    const int kt = t * 64;
    if (t + 1 < NTb) ASTAGE(kt + 64, p ^ 1);

    if (kt < kend) {
      f32x4 s[2][4] = {};
#pragma unroll
      for (int n = 0; n < 4; ++n) {
        const int rowb = (n * 16 + lq) * DIM;
#pragma unroll
        for (int kk = 0; kk < 4; ++kk) {
          const bf16x8 bk = *(const bf16x8*)&sK[p][rowb + ((4 * kk + lg) ^ lq) * 8];
#pragma unroll
          for (int m = 0; m < 2; ++m)
            s[m][n] = __builtin_amdgcn_mfma_f32_16x16x32_bf16(aq[m][kk], bk, s[m][n], 0, 0, 0);
        }
      }
      if (kt + 63 > q0) {
#pragma unroll
        for (int n = 0; n < 4; ++n) {
          const int kpos = kt + n * 16 + lq;
#pragma unroll
          for (int m = 0; m < 2; ++m)
#pragma unroll
            for (int r = 0; r < 4; ++r)
              if (kpos > q0 + m * 16 + lg * 4 + r) s[m][n][r] = -1e30f;
        }
      }
#pragma unroll
      for (int m = 0; m < 2; ++m) {
#pragma unroll
        for (int r = 0; r < 4; ++r) {
          float mx = fmaxf(fmaxf(s[m][0][r], s[m][1][r]), fmaxf(s[m][2][r], s[m][3][r]));
          mx = fmaxf(mx, __shfl_xor(mx, 1));
          mx = fmaxf(mx, __shfl_xor(mx, 2));
          mx = fmaxf(mx, __shfl_xor(mx, 4));
          mx = fmaxf(mx, __shfl_xor(mx, 8));
          const float mnew = fmaxf(mrow[m][r], mx);
          const float alpha = __expf(mrow[m][r] - mnew);
          mrow[m][r] = mnew;
          float rs = 0.0f;
#pragma unroll
          for (int n = 0; n < 4; ++n) {
            const float pv = __expf(s[m][n][r] - mnew);
            s[m][n][r] = pv;
            rs += pv;
          }
          rs += __shfl_xor(rs, 1); rs += __shfl_xor(rs, 2);
          rs += __shfl_xor(rs, 4); rs += __shfl_xor(rs, 8);
          lrow[m][r] = lrow[m][r] * alpha + rs;
#pragma unroll
          for (int f = 0; f < 8; ++f) accO[m][f][r] *= alpha;
        }
      }
#pragma unroll
      for (int m = 0; m < 2; ++m)
#pragma unroll
        for (int n = 0; n < 4; ++n)
#pragma unroll
          for (int r = 0; r < 4; ++r) {
            const int prow = m * 16 + lg * 4 + r;
            const int cb = (n * 16 + lq) * 2;
            const int addr = prow * 128 + (((cb >> 4) ^ (prow & 7)) << 4) + (cb & 15);
            *(__bf16*)((char*)&sP[w][0] + addr) = (__bf16)s[m][n][r];
          }
      asm volatile("s_waitcnt lgkmcnt(0)" ::: "memory");
#pragma unroll
      for (int kk2 = 0; kk2 < 2; ++kk2) {
        bf16x8 ap[2];
#pragma unroll
        for (int m = 0; m < 2; ++m) {
          const int prow = m * 16 + lq;
          ap[m] = *(const bf16x8*)((char*)&sP[w][0] +
                   prow * 128 + (((4 * kk2 + lg) ^ (lq & 7)) << 4));
        }
#pragma unroll
        for (int f = 0; f < 8; ++f) {
          const bf16x8 bv = *(const bf16x8*)&sV[p][(f * 16 + lq) * 64 +
                                                   ((4 * kk2 + lg) ^ (lq & 7)) * 8];
#pragma unroll
          for (int m = 0; m < 2; ++m)
            accO[m][f] = __builtin_amdgcn_mfma_f32_16x16x32_bf16(ap[m], bv, accO[m][f], 0, 0, 0);
        }
      }
    }
    asm volatile("s_waitcnt vmcnt(0)" ::: "memory");
    __builtin_amdgcn_s_barrier();
    p ^= 1;
  }

#pragma unroll
  for (int m = 0; m < 2; ++m)
#pragma unroll
    for (int f = 0; f < 8; ++f)
#pragma unroll
      for (int r = 0; r < 4; ++r) {
        const float v = accO[m][f][r] / lrow[m][r];
        O[((size_t)b * SEQ + q0 + m * 16 + lg * 4 + r) * HIDN + h * DIM + f * 16 + lq] = (__bf16)v;
      }
}

// ---------------- launch ----------------
extern "C" void kernel_launch(void* const* d_in, const int* in_sizes, int n_in,
                              void* d_out, int out_size, void* d_ws, size_t ws_size,
                              hipStream_t stream)
{
  const float* hidden = (const float*)d_in[0];
  const float* cosb   = (const float*)d_in[1];
  const float* sinb   = (const float*)d_in[2];
  const float* w_attn = (const float*)d_in[3];
  const float* b_attn = (const float*)d_in[4];
  const float* w_proj = (const float*)d_in[5];

  char* ws = (char*)d_ws;
  __bf16* hid_bf   = (__bf16*)(ws);                 // [0, 16M)
  __bf16* wattn_bf = (__bf16*)(ws + 16777216);      // [16M, 40M)
  __bf16* wproj_bf = (__bf16*)(ws + 41943040);      // [40M, 48M)
  __bf16* qkv      = (__bf16*)(ws + 50331648);      // [48M, 96M)
  __bf16* Qp       = (__bf16*)(ws);                 // [0, 16M)  (reuse, post-GEMM1)
  __bf16* Kp       = (__bf16*)(ws + 16777216);      // [16M, 32M)
  __bf16* Vt       = (__bf16*)(ws + 100663296);     // [96M, 112M)
  __bf16* Obuf     = (__bf16*)(ws + 117440512);     // [112M, 128M)
  float* out = (float*)d_out;

  f2b_all<<<24576, 256, 0, stream>>>(hidden, hid_bf, w_attn, wattn_bf, w_proj, wproj_bf);

  // qkv = hidden @ w_attn^T + b   (M=4096, N=6144, K=2048): 16x48 = 768 blocks
  gemm_wide<1, __bf16><<<768, 256, 0, stream>>>(
      hid_bf, HIDN, wattn_bf, HIDN, b_attn, qkv, QKVW, HIDN, 16);

  pack_kernel<<<dim3(16, 64), 256, 0, stream>>>(qkv, cosb, sinb, Qp, Kp, Vt);
  attn_kernel<<<dim3(8, 64), 256, 0, stream>>>(Qp, Kp, Vt, Obuf);

  // out = O @ w_proj^T   (M=4096, N=2048, K=2048): 32x16 = 512 blocks, f32 out
  gemm_sq<0, float><<<512, 256, 0, stream>>>(
      Obuf, HIDN, wproj_bf, HIDN, nullptr, out, HIDN, HIDN, 32);
}